// Round 4
// baseline (608.140 us; speedup 1.0000x reference)
//
#include <hip/hip_runtime.h>
#include <hip/hip_bf16.h>
#include <stdint.h>
#include <stddef.h>

#define NN 8192
#define DD 128
#define PANELS 64   // one partial-sum panel per j-tile (grid.x)

typedef __attribute__((ext_vector_type(8))) short bf16x8;
typedef __attribute__((ext_vector_type(4))) float f32x4;

// ---------------------------------------------------------------------------
// Kernel 1: row-normalize features (fp32) and cast to bf16. One wave per row.
// ---------------------------------------------------------------------------
__global__ __launch_bounds__(256) void normalize_kernel(
    const float* __restrict__ f, __hip_bfloat16* __restrict__ fn) {
  const int wave = threadIdx.x >> 6;
  const int lane = threadIdx.x & 63;
  const int row = blockIdx.x * 4 + wave;
  const float2 v = ((const float2*)(f + (size_t)row * DD))[lane];
  float ss = v.x * v.x + v.y * v.y;
#pragma unroll
  for (int m = 1; m < 64; m <<= 1) ss += __shfl_xor(ss, m, 64);
  const float inv = 1.0f / fmaxf(sqrtf(ss), 1e-8f);
  __hip_bfloat162 o;
  o.x = __float2bfloat16(v.x * inv);
  o.y = __float2bfloat16(v.y * inv);
  ((__hip_bfloat162*)(fn + (size_t)row * DD))[lane] = o;
}

// ---------------------------------------------------------------------------
// Kernel 2: one 128x128 sim tile per block; each warp owns 32 ROWS x ALL 128
// columns (acc[2][8]) so every row-sum is intra-warp — no cross-warp combine
// (round-3 bug: wx-split halves collided in the panel store).
//
// Fragment (mt,nt,r) of acc holds sim(i,j) with
//   i = I0 + mt*16 + l16,  j = J0g + nt*16 + quad*4 + r.
// Row-sum over j spans lanes {l16, l16+16, l16+32, l16+48}: 2-shuffle quad
// reduce. No LDS, no barriers, no bf16 round-trip; mask loads unfenced so
// they overlap MFMA across the 16 resident waves/CU.
// ---------------------------------------------------------------------------
template <bool DIAG, bool ATOMIC>
static __device__ __forceinline__ void accum_tile(
    const f32x4 acc[2][8],
    const int* __restrict__ pmask, const int* __restrict__ nmask,
    int I0g, int J0g, int w, int quad, int l16, int panelIdx,
    float* __restrict__ pP, float* __restrict__ nP, float* __restrict__ cP) {
  const float tinv = 1.0f / 0.07f;
#pragma unroll
  for (int mt = 0; mt < 2; ++mt) {
    const int iLoc = w * 32 + mt * 16 + l16;  // local row 0..127
    const size_t mOff = (size_t)(I0g + iLoc) * NN + J0g + quad * 4;
    float pRow = 0.f, qRow = 0.f;
    int cRow = 0;
#pragma unroll
    for (int nt = 0; nt < 8; ++nt) {
      // per-nt mask loads: small live range, compiler pipelines a few deep
      const int4 pm4 = *(const int4*)(pmask + mOff + nt * 16);
      const int4 nm4 = *(const int4*)(nmask + mOff + nt * 16);
      const int dj = DIAG ? (iLoc - (nt * 16 + quad * 4)) : -1;
#pragma unroll
      for (int r = 0; r < 4; ++r) {
        int pm = (&pm4.x)[r];
        int nm = (&nm4.x)[r];
        if (DIAG) {
          if (r == dj) { pm = 0; nm = 0; }  // zero self-contrast
        }
        const float e = __expf(acc[mt][nt][r] * tinv);
        pRow = fmaf(e, (float)pm, pRow);
        qRow = fmaf(e, (float)nm, qRow);
        cRow += pm;
      }
    }
    // quad reduce: lanes l16, l16+16, l16+32, l16+48 hold the 4 j-slices
    pRow += __shfl_xor(pRow, 16, 64);
    pRow += __shfl_xor(pRow, 32, 64);
    qRow += __shfl_xor(qRow, 16, 64);
    qRow += __shfl_xor(qRow, 32, 64);
    cRow += __shfl_xor(cRow, 16, 64);
    cRow += __shfl_xor(cRow, 32, 64);
    const int iG = I0g + iLoc;
    if (ATOMIC) {
      if (quad == 0)      atomicAdd(&pP[iG], pRow);
      else if (quad == 1) atomicAdd(&nP[iG], qRow);
      else if (quad == 2) atomicAdd(&cP[iG], (float)cRow);
    } else {
      const size_t po = (size_t)panelIdx * NN + iG;
      if (quad == 0)      pP[po] = pRow;   // 16 lanes -> 64B coalesced store
      else if (quad == 1) nP[po] = qRow;
      else if (quad == 2) cP[po] = (float)cRow;
    }
  }
}

template <bool ATOMIC>
__global__ __launch_bounds__(256, 4) void ssnt_main(
    const __hip_bfloat16* __restrict__ fn,
    const int* __restrict__ pmask,
    const int* __restrict__ nmask,
    float* __restrict__ pP, float* __restrict__ nP, float* __restrict__ cP) {
  const int tid = threadIdx.x;
  const int lane = tid & 63;
  const int quad = lane >> 4;
  const int l16 = lane & 15;
  const int w = tid >> 6;  // warp 0..3: rows [w*32, w*32+32) of the tile

  const int I0g = blockIdx.y * 128;
  const int J0g = blockIdx.x * 128;
  const int I0 = I0g + w * 32;

  // ---- Phase 1: GEMM (fragments straight from L2; fn is 2 MB) ----
  f32x4 acc[2][8] = {};
#pragma unroll
  for (int kt = 0; kt < 4; ++kt) {
    const int ko = kt * 32 + quad * 8;
    bf16x8 aF[2], bF[8];
#pragma unroll
    for (int mt = 0; mt < 2; ++mt)
      aF[mt] = *(const bf16x8*)(fn + (size_t)(I0 + mt * 16 + l16) * DD + ko);
#pragma unroll
    for (int nt = 0; nt < 8; ++nt)
      bF[nt] = *(const bf16x8*)(fn + (size_t)(J0g + nt * 16 + l16) * DD + ko);
#pragma unroll
    for (int mt = 0; mt < 2; ++mt)
#pragma unroll
      for (int nt = 0; nt < 8; ++nt)
        acc[mt][nt] = __builtin_amdgcn_mfma_f32_16x16x32_bf16(
            bF[nt], aF[mt], acc[mt][nt], 0, 0, 0);  // SWAPPED operands
  }

  // ---- Phase 2: fused exp + masked accumulation (no LDS, no barrier) ----
  if (I0g == J0g)
    accum_tile<true, ATOMIC>(acc, pmask, nmask, I0g, J0g, w, quad, l16,
                             blockIdx.x, pP, nP, cP);
  else
    accum_tile<false, ATOMIC>(acc, pmask, nmask, I0g, J0g, w, quad, l16,
                              blockIdx.x, pP, nP, cP);
}

// ---------------------------------------------------------------------------
// Kernel 3a: reduce panels per row, per-row loss term, block sum -> blkSum[32]
// ---------------------------------------------------------------------------
__global__ __launch_bounds__(256) void finalize1(
    const float* __restrict__ pP, const float* __restrict__ nP,
    const float* __restrict__ cP, int panels, float* __restrict__ blkSum) {
  const int r = blockIdx.x * 256 + threadIdx.x;
  float p = 0.f, q = 0.f, c = 0.f;
  for (int k = 0; k < panels; ++k) {
    p += pP[(size_t)k * NN + r];
    q += nP[(size_t)k * NN + r];
    c += cP[(size_t)k * NN + r];
  }
  float s = logf(p / (p + q)) / c;
#pragma unroll
  for (int m = 1; m < 64; m <<= 1) s += __shfl_xor(s, m, 64);
  __shared__ float ws4[4];
  if ((threadIdx.x & 63) == 0) ws4[threadIdx.x >> 6] = s;
  __syncthreads();
  if (threadIdx.x == 0)
    blkSum[blockIdx.x] = ws4[0] + ws4[1] + ws4[2] + ws4[3];
}

// Kernel 3b: final 32-value sum -> loss
__global__ void finalize2(const float* __restrict__ blkSum,
                          float* __restrict__ out) {
  float s = (threadIdx.x < NN / 256) ? blkSum[threadIdx.x] : 0.f;
#pragma unroll
  for (int m = 1; m < 64; m <<= 1) s += __shfl_xor(s, m, 64);
  if (threadIdx.x == 0) out[0] = -s / (float)NN;
}

extern "C" void kernel_launch(void* const* d_in, const int* in_sizes, int n_in,
                              void* d_out, int out_size, void* d_ws, size_t ws_size,
                              hipStream_t stream) {
  const float* features = (const float*)d_in[0];
  const int* pmask = (const int*)d_in[1];
  const int* nmask = (const int*)d_in[2];
  float* out = (float*)d_out;

  char* ws = (char*)d_ws;
  __hip_bfloat16* fn = (__hip_bfloat16*)ws;  // 2 MB
  float* base = (float*)(ws + (size_t)NN * DD * sizeof(__hip_bfloat16));

  normalize_kernel<<<NN / 4, 256, 0, stream>>>(features, fn);

  const size_t needPanels =
      (size_t)NN * DD * 2 + 3ull * PANELS * NN * sizeof(float) + 256;
  if (ws_size >= needPanels) {
    // panel path: atomic-free, no memset
    float* pP = base;
    float* nP = pP + (size_t)PANELS * NN;
    float* cP = nP + (size_t)PANELS * NN;
    float* blkSum = cP + (size_t)PANELS * NN;
    ssnt_main<false><<<dim3(NN / 128, NN / 128), 256, 0, stream>>>(
        fn, pmask, nmask, pP, nP, cP);
    finalize1<<<NN / 256, 256, 0, stream>>>(pP, nP, cP, PANELS, blkSum);
    finalize2<<<1, 64, 0, stream>>>(blkSum, out);
  } else {
    // fallback: atomic accumulation into [NN] arrays
    float* pP = base;
    float* nP = pP + NN;
    float* cP = nP + NN;
    float* blkSum = cP + NN;
    hipMemsetAsync(pP, 0, 3 * (size_t)NN * sizeof(float), stream);
    ssnt_main<true><<<dim3(NN / 128, NN / 128), 256, 0, stream>>>(
        fn, pmask, nmask, pP, nP, cP);
    finalize1<<<NN / 256, 256, 0, stream>>>(pP, nP, cP, 1, blkSum);
    finalize2<<<1, 64, 0, stream>>>(blkSum, out);
  }
}